// Round 3
// baseline (824.201 us; speedup 1.0000x reference)
//
#include <hip/hip_runtime.h>
#include <stdint.h>

// Problem constants
#define N_POINTS   34100
#define BATCH      8
#define N_GT       200
#define NLEV       5
#define NCAND      3500
#define MAX_DET    300
#define SCORE_TH   0.05f
#define NMS_TH     0.5f
#define IMG        1280.0f
#define TIE_CAP    2048
#define NBIN       4096

// Output layout (float32 flat, reference return order)
#define OUT_MATCH  0        // 8*34100
#define OUT_BOXES  272800   // 8*300*4
#define OUT_SCORES 282400   // 8*300
#define OUT_LABELS 284800   // 8*300
#define OUT_VALID  287200   // 8*300

// Workspace layout (bytes)
#define WS_KEYS    0              // u32[8*34100]   = 1,091,200
#define WS_GHIST   1091200        // u32[40*4096]   =   655,360
#define WS_PARAMS  1746560        // u32[40*2] (T,kk), pad 640
#define WS_CNT     1747200        // u32[64]: [0..7]=defCount, [8..47]=tieCount
#define WS_DEFK    1747456        // u64[8*3584]    =   229,376
#define WS_TIEK    1976832        // u64[40*2048]   =   655,360
#define WS_SBOX    2632192        // float4[8*3500] =   448,000
#define WS_SSC     3080192        // float[8*3500]  =   112,000
#define WS_MASK    3192192        // u64[8*98560]   = 6,307,840
#define MASK_STRIDE 98560         // words per image (packed triangle, padded)
// total ~9.5 MB

typedef unsigned long long u64;
typedef uint32_t u32;

// Packed upper-triangle row offset: row c stores words (c>>6)..54
__device__ __forceinline__ int mask_off(int c) {
    int g = c >> 6;
    return 64 * (55 * g - (g * (g - 1)) / 2) + (c - (g << 6)) * (55 - g);
}

__device__ __forceinline__ int level_of(int p) {
    return (p < 25600) ? 0 : (p < 32000) ? 1 : (p < 33600) ? 2 : (p < 34000) ? 3 : 4;
}
__device__ __forceinline__ int loff_of(int l) {
    return (l == 0) ? 0 : (l == 1) ? 25600 : (l == 2) ? 32000 : (l == 3) ? 33600 : 34000;
}
__device__ __forceinline__ int k_of(int l) {
    return (l == 0) ? 1000 : (l == 1) ? 1000 : (l == 2) ? 1000 : (l == 3) ? 400 : 100;
}

// ---------------------------------------------------------------------------
// Kernel 0: zero histograms + counters (d_ws is poisoned before every launch)
// ---------------------------------------------------------------------------
__global__ __launch_bounds__(256)
void zero_kernel(u32* __restrict__ g) {
    const int n = (WS_CNT + 256 - WS_GHIST) / 4;   // ghist + params + cnt words
    for (int i = blockIdx.x * 256 + threadIdx.x; i < n; i += gridDim.x * 256)
        g[i] = 0u;
}

// ---------------------------------------------------------------------------
// Kernel 1: point->gt matching + sigmoid sortable key + 12-bit histogram.
// ---------------------------------------------------------------------------
__global__ __launch_bounds__(256)
void match_key_kernel(const float* __restrict__ points,
                      const float* __restrict__ gt,
                      const float* __restrict__ logits,
                      float* __restrict__ out_match,
                      u32* __restrict__ keys,
                      u32* __restrict__ ghist) {
#pragma clang fp contract(off)
    __shared__ float bx1[N_GT], by1[N_GT], bx2[N_GT], by2[N_GT], ar[N_GT];
    const int b = blockIdx.y;
    const int p = blockIdx.x * blockDim.x + threadIdx.x;

    for (int j = threadIdx.x; j < N_GT; j += blockDim.x) {
        float x1 = gt[(b * N_GT + j) * 4 + 0];
        float y1 = gt[(b * N_GT + j) * 4 + 1];
        float x2 = gt[(b * N_GT + j) * 4 + 2];
        float y2 = gt[(b * N_GT + j) * 4 + 3];
        bx1[j] = x1; by1[j] = y1; bx2[j] = x2; by2[j] = y2;
        ar[j] = (x2 - x1) * (y2 - y1);
    }
    __syncthreads();
    if (p >= N_POINTS) return;

    const float px = points[p * 2 + 0];
    const float py = points[p * 2 + 1];
    const float BIGF = 2147483648.0f;   // float32(2^31-1) rounds to 2^31
    float best = BIGF;
    int bi = -1;
#pragma unroll 4
    for (int j = 0; j < N_GT; ++j) {
        bool inside = (px >= bx1[j]) && (px <= bx2[j]) &&
                      (py >= by1[j]) && (py <= by2[j]);
        float cost = inside ? ar[j] : BIGF;
        if (cost < best) { best = cost; bi = j; }   // strict < = first-occurrence
    }
    out_match[b * N_POINTS + p] = (float)bi;

    float lg = logits[b * N_POINTS + p];
    float s = 1.0f / (1.0f + expf(-lg));
    u32 u = __float_as_uint(s);
    u32 key = (u & 0x80000000u) ? ~u : (u | 0x80000000u);
    keys[b * N_POINTS + p] = key;

    int seg = b * NLEV + level_of(p);
    atomicAdd(&ghist[seg * NBIN + (key >> 20)], 1u);
}

// ---------------------------------------------------------------------------
// Kernel 2: per-segment threshold select from histogram (one wave per segment).
// Finds T (threshold 12-bit digit) and kk (count needed within digit T).
// ---------------------------------------------------------------------------
__global__ __launch_bounds__(64)
void select_kernel(const u32* __restrict__ ghist, u32* __restrict__ params) {
    const int seg = blockIdx.x;            // b*5 + l
    const int l = seg % NLEV;
    const u32 K = (u32)k_of(l);
    const u32* h = ghist + seg * NBIN;
    const int lane = threadIdx.x;

    u32 S = 0;
#pragma unroll 8
    for (int i = 0; i < 64; ++i) S += h[lane * 64 + i];
    u32 acc = S;                            // suffix-sum over lanes >= lane
#pragma unroll
    for (int off = 1; off < 64; off <<= 1) {
        u32 v = (u32)__shfl_down((int)acc, off);
        if (lane + off < 64) acc += v;
    }
    u32 sfxAfter = acc - S;                 // count in lane-groups > lane
    bool hit = (sfxAfter < K) && (sfxAfter + S >= K);
    u64 bal = __ballot(hit);
    int Lg = (int)__builtin_ctzll(bal);     // unique crossing group
    u32 sfxG = (u32)__shfl((int)sfxAfter, Lg);

    // second level inside group Lg
    u32 v = h[Lg * 64 + lane];
    u32 acc2 = v;
#pragma unroll
    for (int off = 1; off < 64; off <<= 1) {
        u32 t = (u32)__shfl_down((int)acc2, off);
        if (lane + off < 64) acc2 += t;
    }
    u32 sfx2 = sfxG + acc2 - v;             // count of all bins > this bin
    bool hit2 = (sfx2 < K) && (sfx2 + v >= K);
    if (hit2) {
        params[seg * 2 + 0] = (u32)(Lg * 64 + lane);  // T
        params[seg * 2 + 1] = K - sfx2;               // kk within bin T
    }
}

// ---------------------------------------------------------------------------
// Kernel 3: one-pass compact: digit > T -> definite select (per-image list),
// digit == T -> tie list (per-segment). 50-bit global-order key encodes
// (score desc, level asc, idx-in-level asc) and is decodable.
// ---------------------------------------------------------------------------
__global__ __launch_bounds__(256)
void compact_kernel(const u32* __restrict__ keys,
                    const u32* __restrict__ params,
                    u32* __restrict__ cnt,
                    u64* __restrict__ defK,
                    u64* __restrict__ tieK) {
    int idx = blockIdx.x * 256 + threadIdx.x;
    if (idx >= BATCH * N_POINTS) return;
    int b = idx / N_POINTS;
    int p = idx - b * N_POINTS;
    u32 key = keys[idx];
    int l = level_of(p);
    int seg = b * NLEV + l;
    u32 T = params[seg * 2 + 0];
    u32 digit = key >> 20;
    if (digit < T) return;
    int idxl = p - loff_of(l);
    u64 k50 = ((u64)key << 18) | ((u64)(7 - l) << 15) | (u64)(32767 - idxl);
    if (digit > T) {
        u32 pos = atomicAdd(&cnt[b], 1u);
        defK[b * 3584 + pos] = k50;
    } else {
        u32 pos = atomicAdd(&cnt[8 + seg], 1u);
        if (pos < TIE_CAP) tieK[seg * TIE_CAP + pos] = k50;
    }
}

// ---------------------------------------------------------------------------
// Kernel 4: per-image: resolve ties, bitonic-sort 3500 keys (pad 4096) in LDS,
// decode boxes (fp-contract off) into sorted candidate arrays.
// ---------------------------------------------------------------------------
__global__ __launch_bounds__(512)
void sortimg_kernel(const u32* __restrict__ params,
                    const u32* __restrict__ cnt,
                    const u64* __restrict__ defK,
                    const u64* __restrict__ tieK,
                    const float* __restrict__ reg,
                    const float* __restrict__ points,
                    float* __restrict__ sboxes,
                    float* __restrict__ sscores) {
#pragma clang fp contract(off)
    __shared__ u64 sk[4096];
    __shared__ u64 tb[TIE_CAP];
    __shared__ int s_base;
    const int b = blockIdx.x;
    const int tid = threadIdx.x;

    int nd = (int)cnt[b];
    for (int i = tid; i < nd; i += 512) sk[i] = defK[b * 3584 + i];
    if (tid == 0) s_base = nd;
    __syncthreads();

    for (int s = 0; s < NLEV; ++s) {
        int seg = b * NLEV + s;
        int t = (int)cnt[8 + seg];
        if (t > TIE_CAP) t = TIE_CAP;
        int kk = (int)params[seg * 2 + 1];
        for (int i = tid; i < t; i += 512) tb[i] = tieK[seg * TIE_CAP + i];
        __syncthreads();
        int base = s_base;
        for (int j = tid; j < t; j += 512) {
            u64 kj = tb[j];
            int r = 0;
            for (int i = 0; i < t; ++i) r += (tb[i] > kj) ? 1 : 0;
            if (r < kk) sk[base + r] = kj;       // unique ranks -> exact fill
        }
        __syncthreads();
        if (tid == 0) s_base = base + kk;
        __syncthreads();
    }
    const int total = s_base;                    // == 3500 by construction
    for (int i = tid; i < 4096; i += 512)
        if (i >= total) sk[i] = 0ull;
    __syncthreads();

    // bitonic sort, descending (keys unique; zeros sink)
    for (int k = 2; k <= 4096; k <<= 1) {
        for (int j = k >> 1; j > 0; j >>= 1) {
            for (int i = tid; i < 4096; i += 512) {
                int ixj = i ^ j;
                if (ixj > i) {
                    u64 a = sk[i], c = sk[ixj];
                    bool desc = ((i & k) == 0);
                    if (desc ? (a < c) : (a > c)) { sk[i] = c; sk[ixj] = a; }
                }
            }
            __syncthreads();
        }
    }

    // decode + write sorted candidates
    for (int r = tid; r < NCAND; r += 512) {
        float x1 = 0.f, y1 = 0.f, x2 = 0.f, y2 = 0.f, sc = 0.f;
        if (r < total) {
            u64 k50 = sk[r];
            int lowb = (int)(k50 & 0x3FFFFull);
            int l = 7 - (lowb >> 15);
            int idxl = 32767 - (lowb & 32767);
            int p = loff_of(l) + idxl;
            u32 key32 = (u32)(k50 >> 18);
            sc = __uint_as_float(key32 ^ 0x80000000u);
            int gp = b * N_POINTS + p;
            float l_ = reg[gp * 4 + 0] * IMG;
            float t_ = reg[gp * 4 + 1] * IMG;
            float r_ = reg[gp * 4 + 2] * IMG;
            float bb = reg[gp * 4 + 3] * IMG;
            float px = points[p * 2 + 0];
            float py = points[p * 2 + 1];
            x1 = fminf(fmaxf(px - l_, 0.0f), IMG);
            y1 = fminf(fmaxf(py - t_, 0.0f), IMG);
            x2 = fminf(fmaxf(px + r_, 0.0f), IMG);
            y2 = fminf(fmaxf(py + bb, 0.0f), IMG);
        }
        int slot = b * NCAND + r;
        sboxes[slot * 4 + 0] = x1;
        sboxes[slot * 4 + 1] = y1;
        sboxes[slot * 4 + 2] = x2;
        sboxes[slot * 4 + 3] = y2;
        sscores[slot] = sc;
    }
}

// ---------------------------------------------------------------------------
// Kernel 5: suppression-mask matrix, packed upper triangle, 64 IoUs/ballot.
// ---------------------------------------------------------------------------
__global__ __launch_bounds__(256)
void mask_kernel(const float* __restrict__ sboxes,
                 const float* __restrict__ sscores,
                 u64* __restrict__ mask) {
#pragma clang fp contract(off)
    __shared__ float4 sb[3520];
    const int b = blockIdx.y;
    const int tid = threadIdx.x;
    const float4* gb = (const float4*)sboxes + b * NCAND;
    for (int i = tid; i < 3520; i += 256)
        sb[i] = (i < NCAND) ? gb[i] : make_float4(0.f, 0.f, 0.f, 0.f);
    __syncthreads();

    const int lane = tid & 63;
    const int wv = tid >> 6;
    u64* mrow = mask + (size_t)b * MASK_STRIDE;
    const float* ssc = sscores + b * NCAND;
    const int stride = gridDim.x * 4;

    for (int c = blockIdx.x * 4 + wv; c < NCAND; c += stride) {
        if (!(ssc[c] > SCORE_TH)) continue;          // wave-uniform
        float4 bc = sb[c];
        float a1 = (bc.z - bc.x) * (bc.w - bc.y);
        int g = c >> 6;
        int off = mask_off(c);
        for (int w = g; w < 55; ++w) {
            float4 bj = sb[(w << 6) + lane];
            float x1 = fmaxf(bc.x, bj.x);
            float y1 = fmaxf(bc.y, bj.y);
            float x2 = fminf(bc.z, bj.z);
            float y2 = fminf(bc.w, bj.w);
            float inter = fmaxf(x2 - x1, 0.f) * fmaxf(y2 - y1, 0.f);
            float a2 = (bj.z - bj.x) * (bj.w - bj.y);
            float iou = inter / (a1 + a2 - inter + 1e-9f);  // IEEE div
            u64 bits = __ballot(iou > NMS_TH);
            if (lane == 0) mrow[off + (w - g)] = bits;
        }
    }
}

// ---------------------------------------------------------------------------
// Kernel 6: sorted-order NMS scan, two-phase per word:
//   phase 1: keeps via in-wave ballots only (no global loads on the chain)
//   phase 2: batched row ORs, 8 independent loads per vmcnt wait
// ---------------------------------------------------------------------------
__global__ __launch_bounds__(256)
void scan_kernel(const float* __restrict__ sboxes,
                 const float* __restrict__ sscores,
                 const u64* __restrict__ mask,
                 float* __restrict__ out) {
#pragma clang fp contract(off)
    __shared__ float4 sb[3520];
    __shared__ float sl[3520];
    const int b = blockIdx.x;
    const int tid = threadIdx.x;
    const float4* gb = (const float4*)sboxes + b * NCAND;
    const float* gs = sscores + b * NCAND;
    for (int i = tid; i < 3520; i += 256) {
        sb[i] = (i < NCAND) ? gb[i] : make_float4(0.f, 0.f, 0.f, 0.f);
        sl[i] = (i < NCAND) ? gs[i] : 0.f;
    }
    __syncthreads();
    if (tid >= 64) return;               // single wave scans

    const int lane = tid;
    const u64* mrow = mask + (size_t)b * MASK_STRIDE;

    // init: pre-suppress below-threshold / out-of-range
    u64 m = 0ull;
    for (int w = 0; w < 55; ++w) {
        int c = (w << 6) + lane;
        bool bad = !((c < NCAND) && (sl[c] > SCORE_TH));
        u64 bal = __ballot(bad);
        if (lane == w) m = bal;
    }

    float* ob = out + OUT_BOXES  + b * MAX_DET * 4;
    float* os = out + OUT_SCORES + b * MAX_DET;
    float* ol = out + OUT_LABELS + b * MAX_DET;
    float* ov = out + OUT_VALID  + b * MAX_DET;

    int kept = 0;
    for (int w = 0; w < 55 && kept < MAX_DET; ++w) {
        u64 cur = __shfl(m, w);
        if (cur == ~0ull) continue;
        const int wbase = (w << 6);
        const float4 bj = sb[wbase + lane];        // fixed per word
        const float a2j = (bj.z - bj.x) * (bj.w - bj.y);
        u64 km = 0ull;

        // phase 1: keeps via ballots (intra-word suppression recomputed in-wave)
        while (kept < MAX_DET) {
            u64 avail = ~cur;
            if (avail == 0ull) break;
            int t = (int)__builtin_ctzll(avail);
            int c = wbase + t;
            float4 bc = sb[c];
            float a1 = (bc.z - bc.x) * (bc.w - bc.y);
            float x1 = fmaxf(bc.x, bj.x);
            float y1 = fmaxf(bc.y, bj.y);
            float x2 = fminf(bc.z, bj.z);
            float y2 = fminf(bc.w, bj.w);
            float inter = fmaxf(x2 - x1, 0.f) * fmaxf(y2 - y1, 0.f);
            float iou = inter / (a1 + a2j - inter + 1e-9f);
            cur |= __ballot(iou > NMS_TH) | (1ull << t);
            km |= 1ull << t;
            if (lane == 0) {
                ob[kept * 4 + 0] = bc.x;
                ob[kept * 4 + 1] = bc.y;
                ob[kept * 4 + 2] = bc.z;
                ob[kept * 4 + 3] = bc.w;
                os[kept] = sl[c];
                ol[kept] = 0.0f;
                ov[kept] = 1.0f;
            }
            kept++;
        }

        // phase 2: OR kept rows into future words, 8 loads per wait
        if (km) {
            const bool lr = (lane >= w && lane < 55);
            const int lo = lane - w;
            u64 acc = 0ull;
            while (km) {
#define POPBIT(tn) int tn = -1; if (km) { tn = (int)__builtin_ctzll(km); km &= km - 1ull; }
                POPBIT(t0) POPBIT(t1) POPBIT(t2) POPBIT(t3)
                POPBIT(t4) POPBIT(t5) POPBIT(t6) POPBIT(t7)
#undef POPBIT
                u64 v0 = 0, v1 = 0, v2 = 0, v3 = 0, v4 = 0, v5 = 0, v6 = 0, v7 = 0;
                if (lr) {
                    v0 = mrow[mask_off(wbase + t0) + lo];
                    if (t1 >= 0) v1 = mrow[mask_off(wbase + t1) + lo];
                    if (t2 >= 0) v2 = mrow[mask_off(wbase + t2) + lo];
                    if (t3 >= 0) v3 = mrow[mask_off(wbase + t3) + lo];
                    if (t4 >= 0) v4 = mrow[mask_off(wbase + t4) + lo];
                    if (t5 >= 0) v5 = mrow[mask_off(wbase + t5) + lo];
                    if (t6 >= 0) v6 = mrow[mask_off(wbase + t6) + lo];
                    if (t7 >= 0) v7 = mrow[mask_off(wbase + t7) + lo];
                }
                acc |= ((v0 | v1) | (v2 | v3)) | ((v4 | v5) | (v6 | v7));
            }
            m |= acc;
        }
    }
    for (int k = kept + lane; k < MAX_DET; k += 64) {
        ob[k * 4 + 0] = 0.f; ob[k * 4 + 1] = 0.f;
        ob[k * 4 + 2] = 0.f; ob[k * 4 + 3] = 0.f;
        os[k] = 0.f; ol[k] = -1.f; ov[k] = 0.f;
    }
}

// ---------------------------------------------------------------------------
extern "C" void kernel_launch(void* const* d_in, const int* in_sizes, int n_in,
                              void* d_out, int out_size, void* d_ws, size_t ws_size,
                              hipStream_t stream) {
    const float* points = (const float*)d_in[0];
    const float* gt     = (const float*)d_in[1];
    const float* logits = (const float*)d_in[2];
    const float* reg    = (const float*)d_in[3];
    float* out = (float*)d_out;

    u32* keys   = (u32*)((char*)d_ws + WS_KEYS);
    u32* ghist  = (u32*)((char*)d_ws + WS_GHIST);
    u32* params = (u32*)((char*)d_ws + WS_PARAMS);
    u32* cnt    = (u32*)((char*)d_ws + WS_CNT);
    u64* defK   = (u64*)((char*)d_ws + WS_DEFK);
    u64* tieK   = (u64*)((char*)d_ws + WS_TIEK);
    float* sboxes  = (float*)((char*)d_ws + WS_SBOX);
    float* sscores = (float*)((char*)d_ws + WS_SSC);
    u64* mask   = (u64*)((char*)d_ws + WS_MASK);

    zero_kernel<<<256, 256, 0, stream>>>(ghist);

    dim3 g1((N_POINTS + 255) / 256, BATCH);
    match_key_kernel<<<g1, 256, 0, stream>>>(points, gt, logits,
                                             out + OUT_MATCH, keys, ghist);

    select_kernel<<<BATCH * NLEV, 64, 0, stream>>>(ghist, params);

    compact_kernel<<<(BATCH * N_POINTS + 255) / 256, 256, 0, stream>>>(
        keys, params, cnt, defK, tieK);

    sortimg_kernel<<<BATCH, 512, 0, stream>>>(params, cnt, defK, tieK,
                                              reg, points, sboxes, sscores);

    dim3 g5(32, BATCH);
    mask_kernel<<<g5, 256, 0, stream>>>(sboxes, sscores, mask);

    scan_kernel<<<BATCH, 256, 0, stream>>>(sboxes, sscores, mask, out);
}

// Round 4
// 565.346 us; speedup vs baseline: 1.4579x; 1.4579x over previous
//
#include <hip/hip_runtime.h>
#include <stdint.h>

// Problem constants
#define N_POINTS   34100
#define BATCH      8
#define N_GT       200
#define NLEV       5
#define NCAND      3500
#define MAX_DET    300
#define SCORE_TH   0.05f
#define NMS_TH     0.5f
#define IMG        1280.0f
#define TIE_CAP    2048
#define NBIN       4096

// Output layout (float32 flat, reference return order)
#define OUT_MATCH  0        // 8*34100
#define OUT_BOXES  272800   // 8*300*4
#define OUT_SCORES 282400   // 8*300
#define OUT_LABELS 284800   // 8*300
#define OUT_VALID  287200   // 8*300

// Workspace layout (bytes)
#define WS_KEYS    0              // u32[8*34100]   = 1,091,200
#define WS_GHIST   1091200        // u32[40*4096]   =   655,360
#define WS_PARAMS  1746560        // u32[40*2] (T,kk), pad 640
#define WS_CNT     1747200        // u32[64]: [0..7]=defCount, [8..47]=tieCount
#define WS_DEFK    1747456        // u64[8*3584]    =   229,376
#define WS_TIEK    1976832        // u64[40*2048]   =   655,360
#define WS_SBOX    2632192        // float4[8*3500] =   448,000
#define WS_SSC     3080192        // float[8*3500]  =   112,000
#define WS_MASK    3192192        // u64[8*98560]   = 6,307,840
#define MASK_STRIDE 98560         // words per image (packed triangle, padded)
// total ~9.5 MB

typedef unsigned long long u64;
typedef uint32_t u32;

// Packed upper-triangle row offset: row c stores words (c>>6)..54
__device__ __forceinline__ int mask_off(int c) {
    int g = c >> 6;
    return 64 * (55 * g - (g * (g - 1)) / 2) + (c - (g << 6)) * (55 - g);
}

__device__ __forceinline__ int level_of(int p) {
    return (p < 25600) ? 0 : (p < 32000) ? 1 : (p < 33600) ? 2 : (p < 34000) ? 3 : 4;
}
__device__ __forceinline__ int loff_of(int l) {
    return (l == 0) ? 0 : (l == 1) ? 25600 : (l == 2) ? 32000 : (l == 3) ? 33600 : 34000;
}
__device__ __forceinline__ int k_of(int l) {
    return (l == 0) ? 1000 : (l == 1) ? 1000 : (l == 2) ? 1000 : (l == 3) ? 400 : 100;
}

// ---------------------------------------------------------------------------
// Kernel 0: zero histograms + counters (d_ws is poisoned before every launch)
// ---------------------------------------------------------------------------
__global__ __launch_bounds__(256)
void zero_kernel(u32* __restrict__ g) {
    const int n = (WS_CNT + 256 - WS_GHIST) / 4;   // ghist + params + cnt words
    for (int i = blockIdx.x * 256 + threadIdx.x; i < n; i += gridDim.x * 256)
        g[i] = 0u;
}

// ---------------------------------------------------------------------------
// Kernel 1: point->gt matching + sigmoid sortable key + 12-bit histogram.
// ---------------------------------------------------------------------------
__global__ __launch_bounds__(256)
void match_key_kernel(const float* __restrict__ points,
                      const float* __restrict__ gt,
                      const float* __restrict__ logits,
                      float* __restrict__ out_match,
                      u32* __restrict__ keys,
                      u32* __restrict__ ghist) {
#pragma clang fp contract(off)
    __shared__ float bx1[N_GT], by1[N_GT], bx2[N_GT], by2[N_GT], ar[N_GT];
    const int b = blockIdx.y;
    const int p = blockIdx.x * blockDim.x + threadIdx.x;

    for (int j = threadIdx.x; j < N_GT; j += blockDim.x) {
        float x1 = gt[(b * N_GT + j) * 4 + 0];
        float y1 = gt[(b * N_GT + j) * 4 + 1];
        float x2 = gt[(b * N_GT + j) * 4 + 2];
        float y2 = gt[(b * N_GT + j) * 4 + 3];
        bx1[j] = x1; by1[j] = y1; bx2[j] = x2; by2[j] = y2;
        ar[j] = (x2 - x1) * (y2 - y1);
    }
    __syncthreads();
    if (p >= N_POINTS) return;

    const float px = points[p * 2 + 0];
    const float py = points[p * 2 + 1];
    const float BIGF = 2147483648.0f;   // float32(2^31-1) rounds to 2^31
    float best = BIGF;
    int bi = -1;
#pragma unroll 4
    for (int j = 0; j < N_GT; ++j) {
        bool inside = (px >= bx1[j]) && (px <= bx2[j]) &&
                      (py >= by1[j]) && (py <= by2[j]);
        float cost = inside ? ar[j] : BIGF;
        if (cost < best) { best = cost; bi = j; }   // strict < = first-occurrence
    }
    out_match[b * N_POINTS + p] = (float)bi;

    float lg = logits[b * N_POINTS + p];
    float s = 1.0f / (1.0f + expf(-lg));
    u32 u = __float_as_uint(s);
    u32 key = (u & 0x80000000u) ? ~u : (u | 0x80000000u);
    keys[b * N_POINTS + p] = key;

    int seg = b * NLEV + level_of(p);
    atomicAdd(&ghist[seg * NBIN + (key >> 20)], 1u);
}

// ---------------------------------------------------------------------------
// Kernel 2: per-segment threshold select from histogram (one wave per segment).
// Finds T (threshold 12-bit digit) and kk (count needed within digit T).
// ---------------------------------------------------------------------------
__global__ __launch_bounds__(64)
void select_kernel(const u32* __restrict__ ghist, u32* __restrict__ params) {
    const int seg = blockIdx.x;            // b*5 + l
    const int l = seg % NLEV;
    const u32 K = (u32)k_of(l);
    const u32* h = ghist + seg * NBIN;
    const int lane = threadIdx.x;

    u32 S = 0;
#pragma unroll 8
    for (int i = 0; i < 64; ++i) S += h[lane * 64 + i];
    u32 acc = S;                            // suffix-sum over lanes >= lane
#pragma unroll
    for (int off = 1; off < 64; off <<= 1) {
        u32 v = (u32)__shfl_down((int)acc, off);
        if (lane + off < 64) acc += v;
    }
    u32 sfxAfter = acc - S;                 // count in lane-groups > lane
    bool hit = (sfxAfter < K) && (sfxAfter + S >= K);
    u64 bal = __ballot(hit);
    int Lg = (int)__builtin_ctzll(bal);     // unique crossing group
    u32 sfxG = (u32)__shfl((int)sfxAfter, Lg);

    // second level inside group Lg
    u32 v = h[Lg * 64 + lane];
    u32 acc2 = v;
#pragma unroll
    for (int off = 1; off < 64; off <<= 1) {
        u32 t = (u32)__shfl_down((int)acc2, off);
        if (lane + off < 64) acc2 += t;
    }
    u32 sfx2 = sfxG + acc2 - v;             // count of all bins > this bin
    bool hit2 = (sfx2 < K) && (sfx2 + v >= K);
    if (hit2) {
        params[seg * 2 + 0] = (u32)(Lg * 64 + lane);  // T
        params[seg * 2 + 1] = K - sfx2;               // kk within bin T
    }
}

// ---------------------------------------------------------------------------
// Kernel 3: one-pass compact with WAVE-AGGREGATED atomics.
// R3 post-mortem: 28k per-lane atomicAdd-with-return to 48 addresses
// serialized at ~40 cyc/op at the L2 atomic unit -> 311 us. Now: ballot-group
// lanes by destination (<=2 distinct per wave since points are contiguous),
// one atomic per group, position = base + popcount(group & below_me).
// ---------------------------------------------------------------------------
__global__ __launch_bounds__(256)
void compact_kernel(const u32* __restrict__ keys,
                    const u32* __restrict__ params,
                    u32* __restrict__ cnt,
                    u64* __restrict__ defK,
                    u64* __restrict__ tieK) {
    const int idx = blockIdx.x * 256 + threadIdx.x;
    const bool active = idx < BATCH * N_POINTS;
    int b = 0, seg = 0;
    bool isDef = false, isTie = false;
    u64 k50 = 0;
    if (active) {
        b = idx / N_POINTS;
        int p = idx - b * N_POINTS;
        u32 key = keys[idx];
        int l = level_of(p);
        seg = b * NLEV + l;
        u32 T = params[seg * 2 + 0];
        u32 digit = key >> 20;
        int idxl = p - loff_of(l);
        k50 = ((u64)key << 18) | ((u64)(7 - l) << 15) | (u64)(32767 - idxl);
        isDef = digit > T;
        isTie = digit == T;
    }
    const int lane = threadIdx.x & 63;
    const u64 below = (lane == 0) ? 0ull : (~0ull >> (64 - lane));

    // def lists, grouped by image b
    u64 defMask = __ballot(isDef);
    while (defMask) {
        int leader = (int)__builtin_ctzll(defMask);
        int bb = __shfl(b, leader);
        u64 grp = __ballot(isDef && (b == bb));
        u32 base = 0;
        if (lane == leader)
            base = atomicAdd(&cnt[bb], (u32)__builtin_popcountll(grp));
        base = (u32)__shfl((int)base, leader);
        if (isDef && (b == bb)) {
            u32 pos = base + (u32)__builtin_popcountll(grp & below);
            defK[bb * 3584 + pos] = k50;
        }
        defMask &= ~grp;
    }
    // tie lists, grouped by segment
    u64 tieMask = __ballot(isTie);
    while (tieMask) {
        int leader = (int)__builtin_ctzll(tieMask);
        int sg = __shfl(seg, leader);
        u64 grp = __ballot(isTie && (seg == sg));
        u32 base = 0;
        if (lane == leader)
            base = atomicAdd(&cnt[8 + sg], (u32)__builtin_popcountll(grp));
        base = (u32)__shfl((int)base, leader);
        if (isTie && (seg == sg)) {
            u32 pos = base + (u32)__builtin_popcountll(grp & below);
            if (pos < TIE_CAP) tieK[sg * TIE_CAP + pos] = k50;
        }
        tieMask &= ~grp;
    }
}

// ---------------------------------------------------------------------------
// Kernel 4: per-image: resolve ties, bitonic-sort 3500 keys (pad 4096) in LDS,
// decode boxes (fp-contract off) into sorted candidate arrays.
// ---------------------------------------------------------------------------
__global__ __launch_bounds__(512)
void sortimg_kernel(const u32* __restrict__ params,
                    const u32* __restrict__ cnt,
                    const u64* __restrict__ defK,
                    const u64* __restrict__ tieK,
                    const float* __restrict__ reg,
                    const float* __restrict__ points,
                    float* __restrict__ sboxes,
                    float* __restrict__ sscores) {
#pragma clang fp contract(off)
    __shared__ u64 sk[4096];
    __shared__ u64 tb[TIE_CAP];
    __shared__ int s_base;
    const int b = blockIdx.x;
    const int tid = threadIdx.x;

    int nd = (int)cnt[b];
    for (int i = tid; i < nd; i += 512) sk[i] = defK[b * 3584 + i];
    if (tid == 0) s_base = nd;
    __syncthreads();

    for (int s = 0; s < NLEV; ++s) {
        int seg = b * NLEV + s;
        int t = (int)cnt[8 + seg];
        if (t > TIE_CAP) t = TIE_CAP;
        int kk = (int)params[seg * 2 + 1];
        for (int i = tid; i < t; i += 512) tb[i] = tieK[seg * TIE_CAP + i];
        __syncthreads();
        int base = s_base;
        for (int j = tid; j < t; j += 512) {
            u64 kj = tb[j];
            int r = 0;
            for (int i = 0; i < t; ++i) r += (tb[i] > kj) ? 1 : 0;
            if (r < kk) sk[base + r] = kj;       // unique ranks -> exact fill
        }
        __syncthreads();
        if (tid == 0) s_base = base + kk;
        __syncthreads();
    }
    const int total = s_base;                    // == 3500 by construction
    for (int i = tid; i < 4096; i += 512)
        if (i >= total) sk[i] = 0ull;
    __syncthreads();

    // bitonic sort, descending (keys unique; zeros sink)
    for (int k = 2; k <= 4096; k <<= 1) {
        for (int j = k >> 1; j > 0; j >>= 1) {
            for (int i = tid; i < 4096; i += 512) {
                int ixj = i ^ j;
                if (ixj > i) {
                    u64 a = sk[i], c = sk[ixj];
                    bool desc = ((i & k) == 0);
                    if (desc ? (a < c) : (a > c)) { sk[i] = c; sk[ixj] = a; }
                }
            }
            __syncthreads();
        }
    }

    // decode + write sorted candidates
    for (int r = tid; r < NCAND; r += 512) {
        float x1 = 0.f, y1 = 0.f, x2 = 0.f, y2 = 0.f, sc = 0.f;
        if (r < total) {
            u64 k50 = sk[r];
            int lowb = (int)(k50 & 0x3FFFFull);
            int l = 7 - (lowb >> 15);
            int idxl = 32767 - (lowb & 32767);
            int p = loff_of(l) + idxl;
            u32 key32 = (u32)(k50 >> 18);
            sc = __uint_as_float(key32 ^ 0x80000000u);
            int gp = b * N_POINTS + p;
            float l_ = reg[gp * 4 + 0] * IMG;
            float t_ = reg[gp * 4 + 1] * IMG;
            float r_ = reg[gp * 4 + 2] * IMG;
            float bb = reg[gp * 4 + 3] * IMG;
            float px = points[p * 2 + 0];
            float py = points[p * 2 + 1];
            x1 = fminf(fmaxf(px - l_, 0.0f), IMG);
            y1 = fminf(fmaxf(py - t_, 0.0f), IMG);
            x2 = fminf(fmaxf(px + r_, 0.0f), IMG);
            y2 = fminf(fmaxf(py + bb, 0.0f), IMG);
        }
        int slot = b * NCAND + r;
        sboxes[slot * 4 + 0] = x1;
        sboxes[slot * 4 + 1] = y1;
        sboxes[slot * 4 + 2] = x2;
        sboxes[slot * 4 + 3] = y2;
        sscores[slot] = sc;
    }
}

// ---------------------------------------------------------------------------
// Kernel 5: suppression-mask matrix, packed upper triangle, 64 IoUs/ballot.
// ---------------------------------------------------------------------------
__global__ __launch_bounds__(256)
void mask_kernel(const float* __restrict__ sboxes,
                 const float* __restrict__ sscores,
                 u64* __restrict__ mask) {
#pragma clang fp contract(off)
    __shared__ float4 sb[3520];
    const int b = blockIdx.y;
    const int tid = threadIdx.x;
    const float4* gb = (const float4*)sboxes + b * NCAND;
    for (int i = tid; i < 3520; i += 256)
        sb[i] = (i < NCAND) ? gb[i] : make_float4(0.f, 0.f, 0.f, 0.f);
    __syncthreads();

    const int lane = tid & 63;
    const int wv = tid >> 6;
    u64* mrow = mask + (size_t)b * MASK_STRIDE;
    const float* ssc = sscores + b * NCAND;
    const int stride = gridDim.x * 4;

    for (int c = blockIdx.x * 4 + wv; c < NCAND; c += stride) {
        if (!(ssc[c] > SCORE_TH)) continue;          // wave-uniform
        float4 bc = sb[c];
        float a1 = (bc.z - bc.x) * (bc.w - bc.y);
        int g = c >> 6;
        int off = mask_off(c);
        for (int w = g; w < 55; ++w) {
            float4 bj = sb[(w << 6) + lane];
            float x1 = fmaxf(bc.x, bj.x);
            float y1 = fmaxf(bc.y, bj.y);
            float x2 = fminf(bc.z, bj.z);
            float y2 = fminf(bc.w, bj.w);
            float inter = fmaxf(x2 - x1, 0.f) * fmaxf(y2 - y1, 0.f);
            float a2 = (bj.z - bj.x) * (bj.w - bj.y);
            float iou = inter / (a1 + a2 - inter + 1e-9f);  // IEEE div
            u64 bits = __ballot(iou > NMS_TH);
            if (lane == 0) mrow[off + (w - g)] = bits;
        }
    }
}

// ---------------------------------------------------------------------------
// Kernel 6: sorted-order NMS scan, two-phase per word:
//   phase 1: keeps via in-wave ballots only (no global loads on the chain)
//   phase 2: batched row ORs, 8 independent loads per vmcnt wait
// ---------------------------------------------------------------------------
__global__ __launch_bounds__(256)
void scan_kernel(const float* __restrict__ sboxes,
                 const float* __restrict__ sscores,
                 const u64* __restrict__ mask,
                 float* __restrict__ out) {
#pragma clang fp contract(off)
    __shared__ float4 sb[3520];
    __shared__ float sl[3520];
    const int b = blockIdx.x;
    const int tid = threadIdx.x;
    const float4* gb = (const float4*)sboxes + b * NCAND;
    const float* gs = sscores + b * NCAND;
    for (int i = tid; i < 3520; i += 256) {
        sb[i] = (i < NCAND) ? gb[i] : make_float4(0.f, 0.f, 0.f, 0.f);
        sl[i] = (i < NCAND) ? gs[i] : 0.f;
    }
    __syncthreads();
    if (tid >= 64) return;               // single wave scans

    const int lane = tid;
    const u64* mrow = mask + (size_t)b * MASK_STRIDE;

    // init: pre-suppress below-threshold / out-of-range
    u64 m = 0ull;
    for (int w = 0; w < 55; ++w) {
        int c = (w << 6) + lane;
        bool bad = !((c < NCAND) && (sl[c] > SCORE_TH));
        u64 bal = __ballot(bad);
        if (lane == w) m = bal;
    }

    float* ob = out + OUT_BOXES  + b * MAX_DET * 4;
    float* os = out + OUT_SCORES + b * MAX_DET;
    float* ol = out + OUT_LABELS + b * MAX_DET;
    float* ov = out + OUT_VALID  + b * MAX_DET;

    int kept = 0;
    for (int w = 0; w < 55 && kept < MAX_DET; ++w) {
        u64 cur = __shfl(m, w);
        if (cur == ~0ull) continue;
        const int wbase = (w << 6);
        const float4 bj = sb[wbase + lane];        // fixed per word
        const float a2j = (bj.z - bj.x) * (bj.w - bj.y);
        u64 km = 0ull;

        // phase 1: keeps via ballots (intra-word suppression recomputed in-wave)
        while (kept < MAX_DET) {
            u64 avail = ~cur;
            if (avail == 0ull) break;
            int t = (int)__builtin_ctzll(avail);
            int c = wbase + t;
            float4 bc = sb[c];
            float a1 = (bc.z - bc.x) * (bc.w - bc.y);
            float x1 = fmaxf(bc.x, bj.x);
            float y1 = fmaxf(bc.y, bj.y);
            float x2 = fminf(bc.z, bj.z);
            float y2 = fminf(bc.w, bj.w);
            float inter = fmaxf(x2 - x1, 0.f) * fmaxf(y2 - y1, 0.f);
            float iou = inter / (a1 + a2j - inter + 1e-9f);
            cur |= __ballot(iou > NMS_TH) | (1ull << t);
            km |= 1ull << t;
            if (lane == 0) {
                ob[kept * 4 + 0] = bc.x;
                ob[kept * 4 + 1] = bc.y;
                ob[kept * 4 + 2] = bc.z;
                ob[kept * 4 + 3] = bc.w;
                os[kept] = sl[c];
                ol[kept] = 0.0f;
                ov[kept] = 1.0f;
            }
            kept++;
        }

        // phase 2: OR kept rows into future words, 8 loads per wait
        if (km) {
            const bool lr = (lane >= w && lane < 55);
            const int lo = lane - w;
            u64 acc = 0ull;
            while (km) {
#define POPBIT(tn) int tn = -1; if (km) { tn = (int)__builtin_ctzll(km); km &= km - 1ull; }
                POPBIT(t0) POPBIT(t1) POPBIT(t2) POPBIT(t3)
                POPBIT(t4) POPBIT(t5) POPBIT(t6) POPBIT(t7)
#undef POPBIT
                u64 v0 = 0, v1 = 0, v2 = 0, v3 = 0, v4 = 0, v5 = 0, v6 = 0, v7 = 0;
                if (lr) {
                    v0 = mrow[mask_off(wbase + t0) + lo];
                    if (t1 >= 0) v1 = mrow[mask_off(wbase + t1) + lo];
                    if (t2 >= 0) v2 = mrow[mask_off(wbase + t2) + lo];
                    if (t3 >= 0) v3 = mrow[mask_off(wbase + t3) + lo];
                    if (t4 >= 0) v4 = mrow[mask_off(wbase + t4) + lo];
                    if (t5 >= 0) v5 = mrow[mask_off(wbase + t5) + lo];
                    if (t6 >= 0) v6 = mrow[mask_off(wbase + t6) + lo];
                    if (t7 >= 0) v7 = mrow[mask_off(wbase + t7) + lo];
                }
                acc |= ((v0 | v1) | (v2 | v3)) | ((v4 | v5) | (v6 | v7));
            }
            m |= acc;
        }
    }
    for (int k = kept + lane; k < MAX_DET; k += 64) {
        ob[k * 4 + 0] = 0.f; ob[k * 4 + 1] = 0.f;
        ob[k * 4 + 2] = 0.f; ob[k * 4 + 3] = 0.f;
        os[k] = 0.f; ol[k] = -1.f; ov[k] = 0.f;
    }
}

// ---------------------------------------------------------------------------
extern "C" void kernel_launch(void* const* d_in, const int* in_sizes, int n_in,
                              void* d_out, int out_size, void* d_ws, size_t ws_size,
                              hipStream_t stream) {
    const float* points = (const float*)d_in[0];
    const float* gt     = (const float*)d_in[1];
    const float* logits = (const float*)d_in[2];
    const float* reg    = (const float*)d_in[3];
    float* out = (float*)d_out;

    u32* keys   = (u32*)((char*)d_ws + WS_KEYS);
    u32* ghist  = (u32*)((char*)d_ws + WS_GHIST);
    u32* params = (u32*)((char*)d_ws + WS_PARAMS);
    u32* cnt    = (u32*)((char*)d_ws + WS_CNT);
    u64* defK   = (u64*)((char*)d_ws + WS_DEFK);
    u64* tieK   = (u64*)((char*)d_ws + WS_TIEK);
    float* sboxes  = (float*)((char*)d_ws + WS_SBOX);
    float* sscores = (float*)((char*)d_ws + WS_SSC);
    u64* mask   = (u64*)((char*)d_ws + WS_MASK);

    zero_kernel<<<256, 256, 0, stream>>>(ghist);

    dim3 g1((N_POINTS + 255) / 256, BATCH);
    match_key_kernel<<<g1, 256, 0, stream>>>(points, gt, logits,
                                             out + OUT_MATCH, keys, ghist);

    select_kernel<<<BATCH * NLEV, 64, 0, stream>>>(ghist, params);

    compact_kernel<<<(BATCH * N_POINTS + 255) / 256, 256, 0, stream>>>(
        keys, params, cnt, defK, tieK);

    sortimg_kernel<<<BATCH, 512, 0, stream>>>(params, cnt, defK, tieK,
                                              reg, points, sboxes, sscores);

    dim3 g5(32, BATCH);
    mask_kernel<<<g5, 256, 0, stream>>>(sboxes, sscores, mask);

    scan_kernel<<<BATCH, 256, 0, stream>>>(sboxes, sscores, mask, out);
}